// Round 5
// baseline (226.214 us; speedup 1.0000x reference)
//
#include <hip/hip_runtime.h>
#include <hip/hip_bf16.h>

#define B_  16384
#define I_  512
#define H1_ 256
#define H2_ 128
#define E_  8
#define T_  2

typedef __attribute__((ext_vector_type(8))) short short8;
typedef __attribute__((ext_vector_type(4))) float float4_t;

__device__ inline unsigned short f2bf(float f) {
    union { float f; unsigned u; } v; v.f = f;
    unsigned r = v.u + 0x7FFFu + ((v.u >> 16) & 1u);
    return (unsigned short)(r >> 16);
}

// async global->LDS, 16B per lane. LDS dest = wave-uniform base + lane*16.
__device__ inline void async_copy16(const unsigned short* g, unsigned short* l) {
    __builtin_amdgcn_global_load_lds(
        (const __attribute__((address_space(1))) void*)g,
        (__attribute__((address_space(3))) void*)l,
        16, 0, 0);
}

// ================= prep + gates megakernel (one dispatch) =================
// blocks [0,1024):    gates+conv: 16 rows of B each; stage Wg->LDS bf16,
//                     split-K MFMA (4 waves x K=128), LDS reduce, softmax,
//                     write gates[T*E][B] and xb (bf16 x).
// blocks [1024,2048): W1 transpose tiles  [8][512][256] f32 -> [8][256][512] bf16
// blocks [2048,2304): W2 transpose tiles  [8][256][128] f32 -> [8][128][256] bf16
__global__ void prep_gates_kernel(const float* __restrict__ x,
                                  unsigned short* __restrict__ xb,
                                  const float* __restrict__ W1,
                                  unsigned short* __restrict__ w1t,
                                  const float* __restrict__ W2,
                                  unsigned short* __restrict__ w2t,
                                  const float* __restrict__ Wg,
                                  const float* __restrict__ bg,
                                  float* __restrict__ gates) {
    __shared__ __align__(16) char smem[16 * 520 * 2 + 4 * 16 * 16 * 4];  // 20.6 KB
    int bid = blockIdx.x;
    int t = threadIdx.x;

    if (bid < 1024) {
        unsigned short* wgtL = (unsigned short*)smem;          // [16][520] padded
        float (*red)[16][16] = (float (*)[16][16])(smem + 16 * 520 * 2);
        // stage Wg [T][I][E] fp32 -> wgtL[te][i] bf16 (coalesced fp32 reads)
#pragma unroll
        for (int j = 0; j < 32; ++j) {
            int idx = j * 256 + t;               // 0..8191
            int e = idx & 7, i = (idx >> 3) & 511, task = idx >> 12;
            wgtL[(task * 8 + e) * 520 + i] = f2bf(Wg[idx]);
        }
        __syncthreads();

        int w = t >> 6, lane = t & 63;
        int col = lane & 15, quad = lane >> 4;
        int b0 = bid * 16;
        int k0 = w * 128;
        const float* xr = x + (size_t)(b0 + col) * I_ + k0 + quad * 8;
        unsigned short* xw = xb + (size_t)(b0 + col) * I_ + k0 + quad * 8;
        const unsigned short* bL = &wgtL[col * 520 + k0 + quad * 8];
        float4_t acc = {0.f, 0.f, 0.f, 0.f};
#pragma unroll
        for (int ks = 0; ks < 128; ks += 32) {
            float4_t xa = *(const float4_t*)(xr + ks);
            float4_t xc = *(const float4_t*)(xr + ks + 4);
            short8 a;
            a[0] = (short)f2bf(xa[0]); a[1] = (short)f2bf(xa[1]);
            a[2] = (short)f2bf(xa[2]); a[3] = (short)f2bf(xa[3]);
            a[4] = (short)f2bf(xc[0]); a[5] = (short)f2bf(xc[1]);
            a[6] = (short)f2bf(xc[2]); a[7] = (short)f2bf(xc[3]);
            *(short8*)(xw + ks) = a;
            short8 b = *(const short8*)(bL + ks);
            acc = __builtin_amdgcn_mfma_f32_16x16x32_bf16(a, b, acc, 0, 0, 0);
        }
#pragma unroll
        for (int p = 0; p < 4; ++p)
            red[w][quad * 4 + p][col] = acc[p];
        __syncthreads();
        int r = t >> 4, te = t & 15;
        float v = red[0][r][te] + red[1][r][te] + red[2][r][te] + red[3][r][te] + bg[te];
        float m = v;
        m = fmaxf(m, __shfl_xor(m, 1));
        m = fmaxf(m, __shfl_xor(m, 2));
        m = fmaxf(m, __shfl_xor(m, 4));
        float ev = __expf(v - m);
        float s = ev;
        s += __shfl_xor(s, 1);
        s += __shfl_xor(s, 2);
        s += __shfl_xor(s, 4);
        gates[(size_t)te * B_ + b0 + r] = ev / s;
    } else {
        float (*tile)[33] = (float (*)[33])smem;
        const float* in; unsigned short* outp; int R, C, e, r0, c0;
        if (bid < 2048) {
            int tl = bid - 1024;               // 8 e x 16 rblk x 8 cblk
            e = tl >> 7; int rem = tl & 127;
            R = I_; C = H1_;
            r0 = (rem >> 3) * 32; c0 = (rem & 7) * 32;
            in = W1; outp = w1t;
        } else {
            int tl = bid - 2048;               // 8 e x 8 rblk x 4 cblk
            e = tl >> 5; int rem = tl & 31;
            R = H1_; C = H2_;
            r0 = (rem >> 2) * 32; c0 = (rem & 3) * 32;
            in = W2; outp = w2t;
        }
        const float* inp = in + (size_t)e * R * C;
        unsigned short* op = outp + (size_t)e * R * C;
        int tx = t & 31, ty = t >> 5;          // (32, 8)
#pragma unroll
        for (int j = 0; j < 32; j += 8)
            tile[ty + j][tx] = inp[(size_t)(r0 + ty + j) * C + c0 + tx];
        __syncthreads();
#pragma unroll
        for (int j = 0; j < 32; j += 8)
            op[(size_t)(c0 + ty + j) * R + r0 + tx] = f2bf(tile[tx][ty + j]);
    }
}

// ---------------- layer 1 grouped GEMM: h[e] = relu(xb * w1t[e]^T + b1[e]) bf16 ----------------
// 128x128 tile, BK=64, 4 waves of 64x64, 16x16x32 MFMA, XOR-swizzled LDS.
// Epilogue: bias+relu -> padded LDS C-tile (stride 136 kills 4-way write conflict)
// -> coalesced short8 stores.
__global__ void gemm_relu_kernel(const unsigned short* __restrict__ A, size_t aSE,
                                 const unsigned short* __restrict__ Bt, size_t bSE,
                                 const float* __restrict__ bias, int biasSE,
                                 unsigned short* __restrict__ C, size_t cSE,
                                 int K, int lda, int ldb, int ldc) {
    __shared__ unsigned short smem[128 * 136];   // 34 KB: As|Bs (16K shorts), aliased by padded C-tile
    unsigned short* As = smem;                    // 128*64
    unsigned short* Bs = smem + 128 * 64;         // 128*64
    int e = blockIdx.z;
    const unsigned short* Ae = A + (size_t)e * aSE;
    const unsigned short* Be = Bt + (size_t)e * bSE;
    const float* biasE = bias + (size_t)e * biasSE;
    unsigned short* Ce = C + (size_t)e * cSE;
    int m0 = blockIdx.x * 128, n0 = blockIdx.y * 128;
    int t = threadIdx.x, w = t >> 6, lane = t & 63;
    int col = lane & 15, quad = lane >> 4;
    int wm = (w & 1) * 64, wn = (w >> 1) * 64;

    float4_t acc[4][4];
#pragma unroll
    for (int mi = 0; mi < 4; ++mi)
#pragma unroll
        for (int ni = 0; ni < 4; ++ni)
            acc[mi][ni] = (float4_t){0.f, 0.f, 0.f, 0.f};

    int rT = t >> 3;
    int gk = (((t & 7) ^ (rT & 7))) * 8;
    const unsigned short* aG = Ae + (size_t)(m0 + rT) * lda + gk;
    const unsigned short* bG = Be + (size_t)(n0 + rT) * ldb + gk;
    unsigned short* aL = As + (size_t)w * 64 * 8;
    unsigned short* bL = Bs + (size_t)w * 64 * 8;

    for (int k0 = 0; k0 < K; k0 += 64) {
#pragma unroll
        for (int j = 0; j < 4; ++j) {
            async_copy16(aG + (size_t)j * 32 * lda + k0, aL + j * 2048);
            async_copy16(bG + (size_t)j * 32 * ldb + k0, bL + j * 2048);
        }
        __syncthreads();
#pragma unroll
        for (int kk = 0; kk < 64; kk += 32) {
            int q = (kk >> 3) + quad;
            short8 af[4], bf[4];
#pragma unroll
            for (int mi = 0; mi < 4; ++mi) {
                int r = wm + mi * 16 + col;
                af[mi] = *(const short8*)&As[r * 64 + ((q ^ (r & 7)) * 8)];
            }
#pragma unroll
            for (int ni = 0; ni < 4; ++ni) {
                int r = wn + ni * 16 + col;
                bf[ni] = *(const short8*)&Bs[r * 64 + ((q ^ (r & 7)) * 8)];
            }
#pragma unroll
            for (int mi = 0; mi < 4; ++mi)
#pragma unroll
                for (int ni = 0; ni < 4; ++ni)
                    acc[mi][ni] = __builtin_amdgcn_mfma_f32_16x16x32_bf16(af[mi], bf[ni], acc[mi][ni], 0, 0, 0);
        }
        __syncthreads();
    }
    // after final barrier all LDS reads are done -> safe to alias as padded C-tile
    unsigned short* Ct = smem;   // 128 rows x stride 136
#pragma unroll
    for (int ni = 0; ni < 4; ++ni) {
        int c = wn + ni * 16 + col;
        float bv = biasE[n0 + c];
#pragma unroll
        for (int mi = 0; mi < 4; ++mi) {
            int rbase = wm + mi * 16 + quad * 4;
#pragma unroll
            for (int p = 0; p < 4; ++p) {
                float v = acc[mi][ni][p] + bv;
                v = v > 0.f ? v : 0.f;
                Ct[(rbase + p) * 136 + c] = f2bf(v);
            }
        }
    }
    __syncthreads();
    int rr = t >> 4, sl = t & 15;
#pragma unroll
    for (int pass = 0; pass < 8; ++pass) {
        int row = pass * 16 + rr;
        short8 vv = *(const short8*)&Ct[row * 136 + sl * 8];
        *(short8*)&Ce[(size_t)(m0 + row) * ldc + n0 + sl * 8] = vv;
    }
}

// ---------------- fused layer2 + gated combine, barrier-free ----------------
// Block = 16 rows x 128 cols, 4 waves each own 32 n-cols (2 MFMA n-tiles).
// A (h rows) and B (W2t rows) fragments loaded DIRECTLY from global (K-major
// == natural fragment layout; W2t 512KB is L2-resident, h is LLC-hot).
// No LDS staging, no barriers in the loop -> 16 free-running waves/CU.
__global__ void fused_l2_combine_kernel(const unsigned short* __restrict__ h,
                                        const unsigned short* __restrict__ w2t,
                                        const float* __restrict__ b2,
                                        const float* __restrict__ gates,
                                        float* __restrict__ out) {
    __shared__ float gL[16][16];   // [te][row], 1 KB
    int b0 = blockIdx.x * 16;
    int t = threadIdx.x, w = t >> 6, lane = t & 63;
    int col = lane & 15, quad = lane >> 4;
    int wn = w * 32;

    {
        int te = t >> 4, r = t & 15;
        gL[te][r] = gates[(size_t)te * B_ + b0 + r];
    }
    __syncthreads();

    float4_t tw0[2], tw1[2];
#pragma unroll
    for (int nt = 0; nt < 2; ++nt) {
        tw0[nt] = (float4_t){0.f, 0.f, 0.f, 0.f};
        tw1[nt] = (float4_t){0.f, 0.f, 0.f, 0.f};
    }

    const unsigned short* hRow = h + (size_t)(b0 + col) * H1_ + quad * 8;

    for (int e = 0; e < E_; ++e) {
        const unsigned short* hE = hRow + (size_t)e * B_ * H1_;
        const unsigned short* w2E = w2t + ((size_t)e * H2_ + wn + col) * H1_ + quad * 8;

        float4_t acc[2];
        acc[0] = (float4_t){0.f, 0.f, 0.f, 0.f};
        acc[1] = (float4_t){0.f, 0.f, 0.f, 0.f};
#pragma unroll
        for (int kk = 0; kk < H1_; kk += 32) {
            short8 a  = *(const short8*)(hE + kk);
            short8 f0 = *(const short8*)(w2E + kk);
            short8 f1 = *(const short8*)(w2E + (size_t)16 * H1_ + kk);
            acc[0] = __builtin_amdgcn_mfma_f32_16x16x32_bf16(a, f0, acc[0], 0, 0, 0);
            acc[1] = __builtin_amdgcn_mfma_f32_16x16x32_bf16(a, f1, acc[1], 0, 0, 0);
        }

        float bv0 = b2[e * H2_ + wn + col];
        float bv1 = b2[e * H2_ + wn + 16 + col];
#pragma unroll
        for (int p = 0; p < 4; ++p) {
            int r = quad * 4 + p;
            float g0 = gL[e][r], g1 = gL[8 + e][r];
            float v0 = acc[0][p] + bv0; v0 = v0 > 0.f ? v0 : 0.f;
            float v1 = acc[1][p] + bv1; v1 = v1 > 0.f ? v1 : 0.f;
            tw0[0][p] += g0 * v0;  tw0[1][p] += g0 * v1;
            tw1[0][p] += g1 * v0;  tw1[1][p] += g1 * v1;
        }
    }

    // write out [T][B][H2]
#pragma unroll
    for (int nt = 0; nt < 2; ++nt) {
        int n = wn + nt * 16 + col;
#pragma unroll
        for (int p = 0; p < 4; ++p) {
            int r = b0 + quad * 4 + p;
            out[(size_t)r * H2_ + n] = tw0[nt][p];
            out[(size_t)B_ * H2_ + (size_t)r * H2_ + n] = tw1[nt][p];
        }
    }
}

extern "C" void kernel_launch(void* const* d_in, const int* in_sizes, int n_in,
                              void* d_out, int out_size, void* d_ws, size_t ws_size,
                              hipStream_t stream) {
    const float* x  = (const float*)d_in[0];
    const float* W1 = (const float*)d_in[1];
    const float* b1 = (const float*)d_in[2];
    const float* W2 = (const float*)d_in[3];
    const float* b2 = (const float*)d_in[4];
    const float* Wg = (const float*)d_in[5];
    const float* bg = (const float*)d_in[6];
    float* out = (float*)d_out;

    char* ws = (char*)d_ws;
    unsigned short* xb    = (unsigned short*)(ws);                // 16,777,216 B
    unsigned short* w1t   = (unsigned short*)(ws + 16777216);     //  2,097,152 B
    unsigned short* w2t   = (unsigned short*)(ws + 18874368);     //    524,288 B
    float*          gates = (float*)(ws + 19398656);              //  1,048,576 B  [16][B]
    unsigned short* h     = (unsigned short*)(ws + 20447232);     // 67,108,864 B
    // total: 87,556,096 B

    // dispatch 1: all prep + gates (x->bf16, W1^T, W2^T, gate softmax)
    prep_gates_kernel<<<dim3(2304), 256, 0, stream>>>(x, xb, W1, w1t, W2, w2t, Wg, bg, gates);

    // dispatch 2: layer 1: h[e] = relu(xb * w1t[e]^T + b1[e])   M=B, N=H1, K=I
    gemm_relu_kernel<<<dim3(B_ / 128, H1_ / 128, E_), 256, 0, stream>>>(
        xb, 0, w1t, (size_t)H1_ * I_, b1, H1_, h, (size_t)B_ * H1_, I_, I_, I_, H1_);

    // dispatch 3: fused layer 2 + gated combine (barrier-free, direct-from-L2)
    fused_l2_combine_kernel<<<dim3(B_ / 16), 256, 0, stream>>>(h, w2t, b2, gates, out);
}

// Round 6
// 224.093 us; speedup vs baseline: 1.0095x; 1.0095x over previous
//
#include <hip/hip_runtime.h>
#include <hip/hip_bf16.h>

#define B_  16384
#define I_  512
#define H1_ 256
#define H2_ 128
#define E_  8
#define T_  2

typedef __attribute__((ext_vector_type(8))) short short8;
typedef __attribute__((ext_vector_type(4))) float float4_t;

__device__ inline unsigned short f2bf(float f) {
    union { float f; unsigned u; } v; v.f = f;
    unsigned r = v.u + 0x7FFFu + ((v.u >> 16) & 1u);
    return (unsigned short)(r >> 16);
}

// async global->LDS, 16B per lane. LDS dest = wave-uniform base + lane*16.
__device__ inline void async_copy16(const unsigned short* g, unsigned short* l) {
    __builtin_amdgcn_global_load_lds(
        (const __attribute__((address_space(1))) void*)g,
        (__attribute__((address_space(3))) void*)l,
        16, 0, 0);
}

// ================= prep + gates megakernel (one dispatch) =================
__global__ void prep_gates_kernel(const float* __restrict__ x,
                                  unsigned short* __restrict__ xb,
                                  const float* __restrict__ W1,
                                  unsigned short* __restrict__ w1t,
                                  const float* __restrict__ W2,
                                  unsigned short* __restrict__ w2t,
                                  const float* __restrict__ Wg,
                                  const float* __restrict__ bg,
                                  float* __restrict__ gates) {
    __shared__ __align__(16) char smem[16 * 520 * 2 + 4 * 16 * 16 * 4];  // 20.6 KB
    int bid = blockIdx.x;
    int t = threadIdx.x;

    if (bid < 1024) {
        unsigned short* wgtL = (unsigned short*)smem;          // [16][520] padded
        float (*red)[16][16] = (float (*)[16][16])(smem + 16 * 520 * 2);
#pragma unroll
        for (int j = 0; j < 32; ++j) {
            int idx = j * 256 + t;               // 0..8191
            int e = idx & 7, i = (idx >> 3) & 511, task = idx >> 12;
            wgtL[(task * 8 + e) * 520 + i] = f2bf(Wg[idx]);
        }
        __syncthreads();

        int w = t >> 6, lane = t & 63;
        int col = lane & 15, quad = lane >> 4;
        int b0 = bid * 16;
        int k0 = w * 128;
        const float* xr = x + (size_t)(b0 + col) * I_ + k0 + quad * 8;
        unsigned short* xw = xb + (size_t)(b0 + col) * I_ + k0 + quad * 8;
        const unsigned short* bL = &wgtL[col * 520 + k0 + quad * 8];
        float4_t acc = {0.f, 0.f, 0.f, 0.f};
#pragma unroll
        for (int ks = 0; ks < 128; ks += 32) {
            float4_t xa = *(const float4_t*)(xr + ks);
            float4_t xc = *(const float4_t*)(xr + ks + 4);
            short8 a;
            a[0] = (short)f2bf(xa[0]); a[1] = (short)f2bf(xa[1]);
            a[2] = (short)f2bf(xa[2]); a[3] = (short)f2bf(xa[3]);
            a[4] = (short)f2bf(xc[0]); a[5] = (short)f2bf(xc[1]);
            a[6] = (short)f2bf(xc[2]); a[7] = (short)f2bf(xc[3]);
            *(short8*)(xw + ks) = a;
            short8 b = *(const short8*)(bL + ks);
            acc = __builtin_amdgcn_mfma_f32_16x16x32_bf16(a, b, acc, 0, 0, 0);
        }
#pragma unroll
        for (int p = 0; p < 4; ++p)
            red[w][quad * 4 + p][col] = acc[p];
        __syncthreads();
        int r = t >> 4, te = t & 15;
        float v = red[0][r][te] + red[1][r][te] + red[2][r][te] + red[3][r][te] + bg[te];
        float m = v;
        m = fmaxf(m, __shfl_xor(m, 1));
        m = fmaxf(m, __shfl_xor(m, 2));
        m = fmaxf(m, __shfl_xor(m, 4));
        float ev = __expf(v - m);
        float s = ev;
        s += __shfl_xor(s, 1);
        s += __shfl_xor(s, 2);
        s += __shfl_xor(s, 4);
        gates[(size_t)te * B_ + b0 + r] = ev / s;
    } else {
        float (*tile)[33] = (float (*)[33])smem;
        const float* in; unsigned short* outp; int R, C, e, r0, c0;
        if (bid < 2048) {
            int tl = bid - 1024;               // 8 e x 16 rblk x 8 cblk
            e = tl >> 7; int rem = tl & 127;
            R = I_; C = H1_;
            r0 = (rem >> 3) * 32; c0 = (rem & 7) * 32;
            in = W1; outp = w1t;
        } else {
            int tl = bid - 2048;               // 8 e x 8 rblk x 4 cblk
            e = tl >> 5; int rem = tl & 31;
            R = H1_; C = H2_;
            r0 = (rem >> 2) * 32; c0 = (rem & 3) * 32;
            in = W2; outp = w2t;
        }
        const float* inp = in + (size_t)e * R * C;
        unsigned short* op = outp + (size_t)e * R * C;
        int tx = t & 31, ty = t >> 5;          // (32, 8)
#pragma unroll
        for (int j = 0; j < 32; j += 8)
            tile[ty + j][tx] = inp[(size_t)(r0 + ty + j) * C + c0 + tx];
        __syncthreads();
#pragma unroll
        for (int j = 0; j < 32; j += 8)
            op[(size_t)(c0 + ty + j) * R + r0 + tx] = f2bf(tile[tx][ty + j]);
    }
}

// ---------------- layer 1 grouped GEMM: h[e] = relu(xb * w1t[e]^T + b1[e]) bf16 ----------------
__global__ void gemm_relu_kernel(const unsigned short* __restrict__ A, size_t aSE,
                                 const unsigned short* __restrict__ Bt, size_t bSE,
                                 const float* __restrict__ bias, int biasSE,
                                 unsigned short* __restrict__ C, size_t cSE,
                                 int K, int lda, int ldb, int ldc) {
    __shared__ unsigned short smem[128 * 136];   // 34 KB: As|Bs, aliased by padded C-tile
    unsigned short* As = smem;                    // 128*64
    unsigned short* Bs = smem + 128 * 64;         // 128*64
    int e = blockIdx.z;
    const unsigned short* Ae = A + (size_t)e * aSE;
    const unsigned short* Be = Bt + (size_t)e * bSE;
    const float* biasE = bias + (size_t)e * biasSE;
    unsigned short* Ce = C + (size_t)e * cSE;
    int m0 = blockIdx.x * 128, n0 = blockIdx.y * 128;
    int t = threadIdx.x, w = t >> 6, lane = t & 63;
    int col = lane & 15, quad = lane >> 4;
    int wm = (w & 1) * 64, wn = (w >> 1) * 64;

    float4_t acc[4][4];
#pragma unroll
    for (int mi = 0; mi < 4; ++mi)
#pragma unroll
        for (int ni = 0; ni < 4; ++ni)
            acc[mi][ni] = (float4_t){0.f, 0.f, 0.f, 0.f};

    int rT = t >> 3;
    int gk = (((t & 7) ^ (rT & 7))) * 8;
    const unsigned short* aG = Ae + (size_t)(m0 + rT) * lda + gk;
    const unsigned short* bG = Be + (size_t)(n0 + rT) * ldb + gk;
    unsigned short* aL = As + (size_t)w * 64 * 8;
    unsigned short* bL = Bs + (size_t)w * 64 * 8;

    for (int k0 = 0; k0 < K; k0 += 64) {
#pragma unroll
        for (int j = 0; j < 4; ++j) {
            async_copy16(aG + (size_t)j * 32 * lda + k0, aL + j * 2048);
            async_copy16(bG + (size_t)j * 32 * ldb + k0, bL + j * 2048);
        }
        __syncthreads();
#pragma unroll
        for (int kk = 0; kk < 64; kk += 32) {
            int q = (kk >> 3) + quad;
            short8 af[4], bf[4];
#pragma unroll
            for (int mi = 0; mi < 4; ++mi) {
                int r = wm + mi * 16 + col;
                af[mi] = *(const short8*)&As[r * 64 + ((q ^ (r & 7)) * 8)];
            }
#pragma unroll
            for (int ni = 0; ni < 4; ++ni) {
                int r = wn + ni * 16 + col;
                bf[ni] = *(const short8*)&Bs[r * 64 + ((q ^ (r & 7)) * 8)];
            }
#pragma unroll
            for (int mi = 0; mi < 4; ++mi)
#pragma unroll
                for (int ni = 0; ni < 4; ++ni)
                    acc[mi][ni] = __builtin_amdgcn_mfma_f32_16x16x32_bf16(af[mi], bf[ni], acc[mi][ni], 0, 0, 0);
        }
        __syncthreads();
    }
    // after final barrier all LDS reads are done -> safe to alias as padded C-tile
    unsigned short* Ct = smem;   // 128 rows x stride 136
#pragma unroll
    for (int ni = 0; ni < 4; ++ni) {
        int c = wn + ni * 16 + col;
        float bv = biasE[n0 + c];
#pragma unroll
        for (int mi = 0; mi < 4; ++mi) {
            int rbase = wm + mi * 16 + quad * 4;
#pragma unroll
            for (int p = 0; p < 4; ++p) {
                float v = acc[mi][ni][p] + bv;
                v = v > 0.f ? v : 0.f;
                Ct[(rbase + p) * 136 + c] = f2bf(v);
            }
        }
    }
    __syncthreads();
    int rr = t >> 4, sl = t & 15;
#pragma unroll
    for (int pass = 0; pass < 8; ++pass) {
        int row = pass * 16 + rr;
        short8 vv = *(const short8*)&Ct[row * 136 + sl * 8];
        *(short8*)&Ce[(size_t)(m0 + row) * ldc + n0 + sl * 8] = vv;
    }
}

// ---------------- fused layer2 + gated combine, barrier-free, reg-batched ----------------
// Block = 16 rows x 128 cols, 4 waves x 32 n-cols. Per expert: batch-load ALL
// 24 fragments (A 8, B 2x8) into registers (independent loads -> pipelined,
// in-order vmcnt), then 16-MFMA burst. ~140 VGPR, __launch_bounds__(256,3)
// -> 12 waves/CU to hide L2 latency.
__global__ __launch_bounds__(256, 3)
void fused_l2_combine_kernel(const unsigned short* __restrict__ h,
                             const unsigned short* __restrict__ w2t,
                             const float* __restrict__ b2,
                             const float* __restrict__ gates,
                             float* __restrict__ out) {
    __shared__ float gL[16][16];   // [te][row], 1 KB
    int b0 = blockIdx.x * 16;
    int t = threadIdx.x, w = t >> 6, lane = t & 63;
    int col = lane & 15, quad = lane >> 4;
    int wn = w * 32;

    gL[t >> 4][t & 15] = gates[(size_t)(t >> 4) * B_ + b0 + (t & 15)];
    __syncthreads();

    float4_t tw0[2], tw1[2];
#pragma unroll
    for (int nt = 0; nt < 2; ++nt) {
        tw0[nt] = (float4_t){0.f, 0.f, 0.f, 0.f};
        tw1[nt] = (float4_t){0.f, 0.f, 0.f, 0.f};
    }

    const unsigned short* hRow = h + (size_t)(b0 + col) * H1_ + quad * 8;
    const unsigned short* w2Row = w2t + (size_t)(wn + col) * H1_ + quad * 8;

    for (int e = 0; e < E_; ++e) {
        const unsigned short* hE = hRow + (size_t)e * B_ * H1_;
        const unsigned short* w2E = w2Row + (size_t)e * H2_ * H1_;

        // batch all fragment loads (independent -> compiler issues back-to-back)
        short8 af[8], bf0[8], bf1[8];
#pragma unroll
        for (int kk = 0; kk < 8; ++kk) {
            af[kk]  = *(const short8*)(hE + kk * 32);
            bf0[kk] = *(const short8*)(w2E + kk * 32);
            bf1[kk] = *(const short8*)(w2E + (size_t)16 * H1_ + kk * 32);
        }
        float4_t acc0 = {0.f, 0.f, 0.f, 0.f};
        float4_t acc1 = {0.f, 0.f, 0.f, 0.f};
#pragma unroll
        for (int kk = 0; kk < 8; ++kk) {
            acc0 = __builtin_amdgcn_mfma_f32_16x16x32_bf16(af[kk], bf0[kk], acc0, 0, 0, 0);
            acc1 = __builtin_amdgcn_mfma_f32_16x16x32_bf16(af[kk], bf1[kk], acc1, 0, 0, 0);
        }

        float bv0 = b2[e * H2_ + wn + col];
        float bv1 = b2[e * H2_ + wn + 16 + col];
#pragma unroll
        for (int p = 0; p < 4; ++p) {
            int r = quad * 4 + p;
            float g0 = gL[e][r], g1 = gL[8 + e][r];
            float v0 = acc0[p] + bv0; v0 = v0 > 0.f ? v0 : 0.f;
            float v1 = acc1[p] + bv1; v1 = v1 > 0.f ? v1 : 0.f;
            tw0[0][p] += g0 * v0;  tw0[1][p] += g0 * v1;
            tw1[0][p] += g1 * v0;  tw1[1][p] += g1 * v1;
        }
    }

    // write out [T][B][H2]
#pragma unroll
    for (int nt = 0; nt < 2; ++nt) {
        int n = wn + nt * 16 + col;
#pragma unroll
        for (int p = 0; p < 4; ++p) {
            int r = b0 + quad * 4 + p;
            out[(size_t)r * H2_ + n] = tw0[nt][p];
            out[(size_t)B_ * H2_ + (size_t)r * H2_ + n] = tw1[nt][p];
        }
    }
}

extern "C" void kernel_launch(void* const* d_in, const int* in_sizes, int n_in,
                              void* d_out, int out_size, void* d_ws, size_t ws_size,
                              hipStream_t stream) {
    const float* x  = (const float*)d_in[0];
    const float* W1 = (const float*)d_in[1];
    const float* b1 = (const float*)d_in[2];
    const float* W2 = (const float*)d_in[3];
    const float* b2 = (const float*)d_in[4];
    const float* Wg = (const float*)d_in[5];
    const float* bg = (const float*)d_in[6];
    float* out = (float*)d_out;

    char* ws = (char*)d_ws;
    unsigned short* xb    = (unsigned short*)(ws);                // 16,777,216 B
    unsigned short* w1t   = (unsigned short*)(ws + 16777216);     //  2,097,152 B
    unsigned short* w2t   = (unsigned short*)(ws + 18874368);     //    524,288 B
    float*          gates = (float*)(ws + 19398656);              //  1,048,576 B  [16][B]
    unsigned short* h     = (unsigned short*)(ws + 20447232);     // 67,108,864 B
    // total: 87,556,096 B

    // dispatch 1: all prep + gates (x->bf16, W1^T, W2^T, gate softmax)
    prep_gates_kernel<<<dim3(2304), 256, 0, stream>>>(x, xb, W1, w1t, W2, w2t, Wg, bg, gates);

    // dispatch 2: layer 1: h[e] = relu(xb * w1t[e]^T + b1[e])   M=B, N=H1, K=I
    gemm_relu_kernel<<<dim3(B_ / 128, H1_ / 128, E_), 256, 0, stream>>>(
        xb, 0, w1t, (size_t)H1_ * I_, b1, H1_, h, (size_t)B_ * H1_, I_, I_, I_, H1_);

    // dispatch 3: fused layer 2 + gated combine (reg-batched, barrier-free)
    fused_l2_combine_kernel<<<dim3(B_ / 16), 256, 0, stream>>>(h, w2t, b2, gates, out);
}

// Round 7
// 221.055 us; speedup vs baseline: 1.0233x; 1.0137x over previous
//
#include <hip/hip_runtime.h>
#include <hip/hip_bf16.h>

#define B_  16384
#define I_  512
#define H1_ 256
#define H2_ 128
#define E_  8
#define T_  2

typedef __attribute__((ext_vector_type(8))) short short8;
typedef __attribute__((ext_vector_type(4))) float float4_t;

__device__ inline unsigned short f2bf(float f) {
    union { float f; unsigned u; } v; v.f = f;
    unsigned r = v.u + 0x7FFFu + ((v.u >> 16) & 1u);
    return (unsigned short)(r >> 16);
}

// async global->LDS, 16B per lane. LDS dest = wave-uniform base + lane*16.
__device__ inline void async_copy16(const unsigned short* g, unsigned short* l) {
    __builtin_amdgcn_global_load_lds(
        (const __attribute__((address_space(1))) void*)g,
        (__attribute__((address_space(3))) void*)l,
        16, 0, 0);
}

// ================= prep + gates megakernel (one dispatch) =================
__global__ void prep_gates_kernel(const float* __restrict__ x,
                                  unsigned short* __restrict__ xb,
                                  const float* __restrict__ W1,
                                  unsigned short* __restrict__ w1t,
                                  const float* __restrict__ W2,
                                  unsigned short* __restrict__ w2t,
                                  const float* __restrict__ Wg,
                                  const float* __restrict__ bg,
                                  float* __restrict__ gates) {
    __shared__ __align__(16) char smem[16 * 520 * 2 + 4 * 16 * 16 * 4];  // 20.6 KB
    int bid = blockIdx.x;
    int t = threadIdx.x;

    if (bid < 1024) {
        unsigned short* wgtL = (unsigned short*)smem;          // [16][520] padded
        float (*red)[16][16] = (float (*)[16][16])(smem + 16 * 520 * 2);
#pragma unroll
        for (int j = 0; j < 32; ++j) {
            int idx = j * 256 + t;               // 0..8191
            int e = idx & 7, i = (idx >> 3) & 511, task = idx >> 12;
            wgtL[(task * 8 + e) * 520 + i] = f2bf(Wg[idx]);
        }
        __syncthreads();

        int w = t >> 6, lane = t & 63;
        int col = lane & 15, quad = lane >> 4;
        int b0 = bid * 16;
        int k0 = w * 128;
        const float* xr = x + (size_t)(b0 + col) * I_ + k0 + quad * 8;
        unsigned short* xw = xb + (size_t)(b0 + col) * I_ + k0 + quad * 8;
        const unsigned short* bL = &wgtL[col * 520 + k0 + quad * 8];
        float4_t acc = {0.f, 0.f, 0.f, 0.f};
#pragma unroll
        for (int ks = 0; ks < 128; ks += 32) {
            float4_t xa = *(const float4_t*)(xr + ks);
            float4_t xc = *(const float4_t*)(xr + ks + 4);
            short8 a;
            a[0] = (short)f2bf(xa[0]); a[1] = (short)f2bf(xa[1]);
            a[2] = (short)f2bf(xa[2]); a[3] = (short)f2bf(xa[3]);
            a[4] = (short)f2bf(xc[0]); a[5] = (short)f2bf(xc[1]);
            a[6] = (short)f2bf(xc[2]); a[7] = (short)f2bf(xc[3]);
            *(short8*)(xw + ks) = a;
            short8 b = *(const short8*)(bL + ks);
            acc = __builtin_amdgcn_mfma_f32_16x16x32_bf16(a, b, acc, 0, 0, 0);
        }
#pragma unroll
        for (int p = 0; p < 4; ++p)
            red[w][quad * 4 + p][col] = acc[p];
        __syncthreads();
        int r = t >> 4, te = t & 15;
        float v = red[0][r][te] + red[1][r][te] + red[2][r][te] + red[3][r][te] + bg[te];
        float m = v;
        m = fmaxf(m, __shfl_xor(m, 1));
        m = fmaxf(m, __shfl_xor(m, 2));
        m = fmaxf(m, __shfl_xor(m, 4));
        float ev = __expf(v - m);
        float s = ev;
        s += __shfl_xor(s, 1);
        s += __shfl_xor(s, 2);
        s += __shfl_xor(s, 4);
        gates[(size_t)te * B_ + b0 + r] = ev / s;
    } else {
        float (*tile)[33] = (float (*)[33])smem;
        const float* in; unsigned short* outp; int R, C, e, r0, c0;
        if (bid < 2048) {
            int tl = bid - 1024;               // 8 e x 16 rblk x 8 cblk
            e = tl >> 7; int rem = tl & 127;
            R = I_; C = H1_;
            r0 = (rem >> 3) * 32; c0 = (rem & 7) * 32;
            in = W1; outp = w1t;
        } else {
            int tl = bid - 2048;               // 8 e x 8 rblk x 4 cblk
            e = tl >> 5; int rem = tl & 31;
            R = H1_; C = H2_;
            r0 = (rem >> 2) * 32; c0 = (rem & 3) * 32;
            in = W2; outp = w2t;
        }
        const float* inp = in + (size_t)e * R * C;
        unsigned short* op = outp + (size_t)e * R * C;
        int tx = t & 31, ty = t >> 5;          // (32, 8)
#pragma unroll
        for (int j = 0; j < 32; j += 8)
            tile[ty + j][tx] = inp[(size_t)(r0 + ty + j) * C + c0 + tx];
        __syncthreads();
#pragma unroll
        for (int j = 0; j < 32; j += 8)
            op[(size_t)(c0 + ty + j) * R + r0 + tx] = f2bf(tile[tx][ty + j]);
    }
}

// ---------------- layer 1 grouped GEMM: h[e] = relu(xb * w1t[e]^T + b1[e]) bf16 ----------------
__global__ void gemm_relu_kernel(const unsigned short* __restrict__ A, size_t aSE,
                                 const unsigned short* __restrict__ Bt, size_t bSE,
                                 const float* __restrict__ bias, int biasSE,
                                 unsigned short* __restrict__ C, size_t cSE,
                                 int K, int lda, int ldb, int ldc) {
    __shared__ unsigned short smem[128 * 136];   // 34 KB: As|Bs, aliased by padded C-tile
    unsigned short* As = smem;                    // 128*64
    unsigned short* Bs = smem + 128 * 64;         // 128*64
    int e = blockIdx.z;
    const unsigned short* Ae = A + (size_t)e * aSE;
    const unsigned short* Be = Bt + (size_t)e * bSE;
    const float* biasE = bias + (size_t)e * biasSE;
    unsigned short* Ce = C + (size_t)e * cSE;
    int m0 = blockIdx.x * 128, n0 = blockIdx.y * 128;
    int t = threadIdx.x, w = t >> 6, lane = t & 63;
    int col = lane & 15, quad = lane >> 4;
    int wm = (w & 1) * 64, wn = (w >> 1) * 64;

    float4_t acc[4][4];
#pragma unroll
    for (int mi = 0; mi < 4; ++mi)
#pragma unroll
        for (int ni = 0; ni < 4; ++ni)
            acc[mi][ni] = (float4_t){0.f, 0.f, 0.f, 0.f};

    int rT = t >> 3;
    int gk = (((t & 7) ^ (rT & 7))) * 8;
    const unsigned short* aG = Ae + (size_t)(m0 + rT) * lda + gk;
    const unsigned short* bG = Be + (size_t)(n0 + rT) * ldb + gk;
    unsigned short* aL = As + (size_t)w * 64 * 8;
    unsigned short* bL = Bs + (size_t)w * 64 * 8;

    for (int k0 = 0; k0 < K; k0 += 64) {
#pragma unroll
        for (int j = 0; j < 4; ++j) {
            async_copy16(aG + (size_t)j * 32 * lda + k0, aL + j * 2048);
            async_copy16(bG + (size_t)j * 32 * ldb + k0, bL + j * 2048);
        }
        __syncthreads();
#pragma unroll
        for (int kk = 0; kk < 64; kk += 32) {
            int q = (kk >> 3) + quad;
            short8 af[4], bf[4];
#pragma unroll
            for (int mi = 0; mi < 4; ++mi) {
                int r = wm + mi * 16 + col;
                af[mi] = *(const short8*)&As[r * 64 + ((q ^ (r & 7)) * 8)];
            }
#pragma unroll
            for (int ni = 0; ni < 4; ++ni) {
                int r = wn + ni * 16 + col;
                bf[ni] = *(const short8*)&Bs[r * 64 + ((q ^ (r & 7)) * 8)];
            }
#pragma unroll
            for (int mi = 0; mi < 4; ++mi)
#pragma unroll
                for (int ni = 0; ni < 4; ++ni)
                    acc[mi][ni] = __builtin_amdgcn_mfma_f32_16x16x32_bf16(af[mi], bf[ni], acc[mi][ni], 0, 0, 0);
        }
        __syncthreads();
    }
    // after final barrier all LDS reads are done -> safe to alias as padded C-tile
    unsigned short* Ct = smem;   // 128 rows x stride 136
#pragma unroll
    for (int ni = 0; ni < 4; ++ni) {
        int c = wn + ni * 16 + col;
        float bv = biasE[n0 + c];
#pragma unroll
        for (int mi = 0; mi < 4; ++mi) {
            int rbase = wm + mi * 16 + quad * 4;
#pragma unroll
            for (int p = 0; p < 4; ++p) {
                float v = acc[mi][ni][p] + bv;
                v = v > 0.f ? v : 0.f;
                Ct[(rbase + p) * 136 + c] = f2bf(v);
            }
        }
    }
    __syncthreads();
    int rr = t >> 4, sl = t & 15;
#pragma unroll
    for (int pass = 0; pass < 8; ++pass) {
        int row = pass * 16 + rr;
        short8 vv = *(const short8*)&Ct[row * 136 + sl * 8];
        *(short8*)&Ce[(size_t)(m0 + row) * ldc + n0 + sl * 8] = vv;
    }
}

// ---------------- fused layer2 + gated combine, barrier-free, sched-pinned ----------------
// Block = 16 rows x 128 cols, 4 waves x 32 n-cols. Per expert: batch-issue ALL
// 24 fragment loads, then sched_barrier(0) pins them BEFORE the MFMA burst --
// forcing the register allocator to keep ~96 VGPRs of fragments live (R5/R6
// showed the compiler otherwise sinks each load next to its use -> serial
// chain, VGPR=56, 91 us). Loads of expert e+1 may still overlap MFMAs of e
// (both sit between consecutive barriers).
__global__ __launch_bounds__(256, 2)
void fused_l2_combine_kernel(const unsigned short* __restrict__ h,
                             const unsigned short* __restrict__ w2t,
                             const float* __restrict__ b2,
                             const float* __restrict__ gates,
                             float* __restrict__ out) {
    __shared__ float gL[16][16];   // [te][row], 1 KB
    int b0 = blockIdx.x * 16;
    int t = threadIdx.x, w = t >> 6, lane = t & 63;
    int col = lane & 15, quad = lane >> 4;
    int wn = w * 32;

    gL[t >> 4][t & 15] = gates[(size_t)(t >> 4) * B_ + b0 + (t & 15)];
    __syncthreads();

    float4_t tw0[2], tw1[2];
#pragma unroll
    for (int nt = 0; nt < 2; ++nt) {
        tw0[nt] = (float4_t){0.f, 0.f, 0.f, 0.f};
        tw1[nt] = (float4_t){0.f, 0.f, 0.f, 0.f};
    }

    const unsigned short* hRow = h + (size_t)(b0 + col) * H1_ + quad * 8;
    const unsigned short* w2Row = w2t + (size_t)(wn + col) * H1_ + quad * 8;

#pragma unroll
    for (int e = 0; e < E_; ++e) {
        const unsigned short* hE = hRow + (size_t)e * B_ * H1_;
        const unsigned short* w2E = w2Row + (size_t)e * H2_ * H1_;

        // batch all 24 fragment loads back-to-back
        short8 af[8], bf0[8], bf1[8];
#pragma unroll
        for (int kk = 0; kk < 8; ++kk) {
            af[kk]  = *(const short8*)(hE + kk * 32);
            bf0[kk] = *(const short8*)(w2E + kk * 32);
            bf1[kk] = *(const short8*)(w2E + (size_t)16 * H1_ + kk * 32);
        }
        // pin: nothing crosses -> loads stay clustered before the MFMA burst
        __builtin_amdgcn_sched_barrier(0);

        float4_t acc0 = {0.f, 0.f, 0.f, 0.f};
        float4_t acc1 = {0.f, 0.f, 0.f, 0.f};
#pragma unroll
        for (int kk = 0; kk < 8; ++kk) {
            acc0 = __builtin_amdgcn_mfma_f32_16x16x32_bf16(af[kk], bf0[kk], acc0, 0, 0, 0);
            acc1 = __builtin_amdgcn_mfma_f32_16x16x32_bf16(af[kk], bf1[kk], acc1, 0, 0, 0);
        }

        float bv0 = b2[e * H2_ + wn + col];
        float bv1 = b2[e * H2_ + wn + 16 + col];
#pragma unroll
        for (int p = 0; p < 4; ++p) {
            int r = quad * 4 + p;
            float g0 = gL[e][r], g1 = gL[8 + e][r];
            float v0 = acc0[p] + bv0; v0 = v0 > 0.f ? v0 : 0.f;
            float v1 = acc1[p] + bv1; v1 = v1 > 0.f ? v1 : 0.f;
            tw0[0][p] += g0 * v0;  tw0[1][p] += g0 * v1;
            tw1[0][p] += g1 * v0;  tw1[1][p] += g1 * v1;
        }
    }

    // write out [T][B][H2]
#pragma unroll
    for (int nt = 0; nt < 2; ++nt) {
        int n = wn + nt * 16 + col;
#pragma unroll
        for (int p = 0; p < 4; ++p) {
            int r = b0 + quad * 4 + p;
            out[(size_t)r * H2_ + n] = tw0[nt][p];
            out[(size_t)B_ * H2_ + (size_t)r * H2_ + n] = tw1[nt][p];
        }
    }
}

extern "C" void kernel_launch(void* const* d_in, const int* in_sizes, int n_in,
                              void* d_out, int out_size, void* d_ws, size_t ws_size,
                              hipStream_t stream) {
    const float* x  = (const float*)d_in[0];
    const float* W1 = (const float*)d_in[1];
    const float* b1 = (const float*)d_in[2];
    const float* W2 = (const float*)d_in[3];
    const float* b2 = (const float*)d_in[4];
    const float* Wg = (const float*)d_in[5];
    const float* bg = (const float*)d_in[6];
    float* out = (float*)d_out;

    char* ws = (char*)d_ws;
    unsigned short* xb    = (unsigned short*)(ws);                // 16,777,216 B
    unsigned short* w1t   = (unsigned short*)(ws + 16777216);     //  2,097,152 B
    unsigned short* w2t   = (unsigned short*)(ws + 18874368);     //    524,288 B
    float*          gates = (float*)(ws + 19398656);              //  1,048,576 B  [16][B]
    unsigned short* h     = (unsigned short*)(ws + 20447232);     // 67,108,864 B
    // total: 87,556,096 B

    // dispatch 1: all prep + gates (x->bf16, W1^T, W2^T, gate softmax)
    prep_gates_kernel<<<dim3(2304), 256, 0, stream>>>(x, xb, W1, w1t, W2, w2t, Wg, bg, gates);

    // dispatch 2: layer 1: h[e] = relu(xb * w1t[e]^T + b1[e])   M=B, N=H1, K=I
    gemm_relu_kernel<<<dim3(B_ / 128, H1_ / 128, E_), 256, 0, stream>>>(
        xb, 0, w1t, (size_t)H1_ * I_, b1, H1_, h, (size_t)B_ * H1_, I_, I_, I_, H1_);

    // dispatch 3: fused layer 2 + gated combine (sched-pinned reg batch)
    fused_l2_combine_kernel<<<dim3(B_ / 16), 256, 0, stream>>>(h, w2t, b2, gates, out);
}